// Round 1
// baseline (246.892 us; speedup 1.0000x reference)
//
#include <hip/hip_runtime.h>
#include <math.h>

#define BSZ   256
#define RANK  16
#define IN_D  784
#define H1D   512
#define OUT_D 10
#define TOTAL 29610

// g layout offsets (per batch row of TOTAL)
#define OFF_A1    0        // 512*16 = 8192
#define OFF_B1F   8192     // 16*784 = 12544
#define OFF_BIAS1 20736    // 512
#define OFF_A2    21248    // 10*16 = 160
#define OFF_B2F   21408    // 16*512 = 8192
#define OFF_BIAS2 29600    // 10

// ---------------- conv1: (256,1,28,28) -> relu -> (256,16,14,14) ----------------
__global__ void conv1_k(const float* __restrict__ img, const float* __restrict__ w,
                        const float* __restrict__ bias, float* __restrict__ out) {
    int idx = blockIdx.x * 256 + threadIdx.x;
    if (idx >= BSZ * 16 * 14 * 14) return;
    int ox = idx % 14, oy = (idx / 14) % 14, oc = (idx / 196) % 16, b = idx / (196 * 16);
    float acc = bias[oc];
    const float* ib = img + b * 784;
    const float* wb = w + oc * 9;
#pragma unroll
    for (int ky = 0; ky < 3; ky++) {
        int iy = oy * 2 - 1 + ky;
        if ((unsigned)iy < 28u) {
#pragma unroll
            for (int kx = 0; kx < 3; kx++) {
                int ix = ox * 2 - 1 + kx;
                if ((unsigned)ix < 28u) acc += ib[iy * 28 + ix] * wb[ky * 3 + kx];
            }
        }
    }
    out[idx] = fmaxf(acc, 0.f);
}

// ---------------- conv2: (256,16,14,14) -> relu -> (256,32,7,7) ----------------
__global__ void conv2_k(const float* __restrict__ in, const float* __restrict__ w,
                        const float* __restrict__ bias, float* __restrict__ out) {
    int idx = blockIdx.x * 256 + threadIdx.x;
    if (idx >= BSZ * 32 * 7 * 7) return;
    int ox = idx % 7, oy = (idx / 7) % 7, oc = (idx / 49) % 32, b = idx / (49 * 32);
    float acc = bias[oc];
    const float* ib = in + b * 16 * 196;
    const float* wb = w + oc * 16 * 9;
    for (int ic = 0; ic < 16; ic++) {
        const float* ibc = ib + ic * 196;
        const float* wbc = wb + ic * 9;
#pragma unroll
        for (int ky = 0; ky < 3; ky++) {
            int iy = oy * 2 - 1 + ky;
            if ((unsigned)iy < 14u) {
#pragma unroll
                for (int kx = 0; kx < 3; kx++) {
                    int ix = ox * 2 - 1 + kx;
                    if ((unsigned)ix < 14u) acc += ibc[iy * 14 + ix] * wbc[ky * 3 + kx];
                }
            }
        }
    }
    out[idx] = fmaxf(acc, 0.f);
}

// ---------------- style = tanh(h2 @ sew.T + seb); s128 = relu(style @ g1w.T + g1b) ----------------
// one block (256 thr) per batch
__global__ void se_g1_k(const float* __restrict__ h2, const float* __restrict__ sew,
                        const float* __restrict__ seb, const float* __restrict__ g1w,
                        const float* __restrict__ g1b, float* __restrict__ s128) {
    __shared__ float hrow[1568];
    __shared__ float red[64 * 4];
    __shared__ float style[64];
    int b = blockIdx.x, tid = threadIdx.x;
    for (int i = tid; i < 1568; i += 256) hrow[i] = h2[b * 1568 + i];
    __syncthreads();
    {
        int j = tid & 63, p = tid >> 6;  // 4 partials per output
        const float* wr = sew + j * 1568;
        float acc = 0.f;
        for (int k = p * 392; k < (p + 1) * 392; k++) acc += wr[k] * hrow[k];
        red[j * 4 + p] = acc;
    }
    __syncthreads();
    if (tid < 64) {
        float a = red[tid * 4] + red[tid * 4 + 1] + red[tid * 4 + 2] + red[tid * 4 + 3] + seb[tid];
        style[tid] = tanhf(a);
    }
    __syncthreads();
    if (tid < 128) {
        const float* wr = g1w + tid * 64;
        float acc = g1b[tid];
#pragma unroll
        for (int k = 0; k < 64; k++) acc += wr[k] * style[k];
        s128[b * 128 + tid] = fmaxf(acc, 0.f);
    }
}

// ---------------- g[b][t] = dot128(s128[b], g2w[t]) + g2b[t] ----------------
// block: 256 threads; each thread owns t and t+256 (2 rows) x 16 batches.
// s-tile (16x128) in LDS, broadcast reads -> 8 FMA per ds_read_b128.
__global__ void gmm_k(const float* __restrict__ s128, const float* __restrict__ g2w,
                      const float* __restrict__ g2b, float* __restrict__ g) {
    __shared__ float sl[16 * 128];
    int tid = threadIdx.x;
    int tb0 = blockIdx.y * 16;
    int t = blockIdx.x * 512 + tid;
    for (int i = tid; i < 2048; i += 256) sl[i] = s128[tb0 * 128 + i];
    __syncthreads();
    if (t >= TOTAL) return;
    int t2 = t + 256;
    bool has2 = (t2 < TOTAL);
    const float4* wa = (const float4*)(g2w + t * 128);
    const float4* wb = has2 ? (const float4*)(g2w + t2 * 128) : wa;
    const float4* s4 = (const float4*)sl;
    float b1 = g2b[t];
    float b2 = has2 ? g2b[t2] : 0.f;
    float acc[2][16];
#pragma unroll
    for (int j = 0; j < 16; j++) { acc[0][j] = b1; acc[1][j] = b2; }
    for (int kk = 0; kk < 32; kk++) {
        float4 w0 = wa[kk];
        float4 w1 = wb[kk];
#pragma unroll
        for (int j = 0; j < 16; j++) {
            float4 s = s4[j * 32 + kk];
            acc[0][j] += w0.x * s.x + w0.y * s.y + w0.z * s.z + w0.w * s.w;
            acc[1][j] += w1.x * s.x + w1.y * s.y + w1.z * s.z + w1.w * s.w;
        }
    }
#pragma unroll
    for (int j = 0; j < 16; j++) {
        g[(tb0 + j) * TOTAL + t] = acc[0][j];
        if (has2) g[(tb0 + j) * TOTAL + t2] = acc[1][j];
    }
}

// ---------------- per-batch low-rank apply ----------------
// h1 = relu(a1 @ (b1f @ x) + bias1); out = a2 @ (b2f @ h1) + bias2
__global__ void apply_k(const float* __restrict__ img, const float* __restrict__ g,
                        float* __restrict__ out) {
    __shared__ float x[IN_D];
    __shared__ float red[16 * 16];
    __shared__ float v1[RANK];
    __shared__ float h1s[H1D];
    __shared__ float v2[RANK];
    int b = blockIdx.x, tid = threadIdx.x;
    const float* gb = g + b * TOTAL;
    for (int i = tid; i < IN_D; i += 256) x[i] = img[b * IN_D + i];
    __syncthreads();
    // v1[r] = sum_i b1f[r,i] * x[i]
    {
        int r = tid >> 4, p = tid & 15;
        const float* row = gb + OFF_B1F + r * IN_D;
        float acc = 0.f;
        for (int i = p; i < IN_D; i += 16) acc += row[i] * x[i];
        red[tid] = acc;
    }
    __syncthreads();
    if (tid < 16) {
        float s = 0.f;
#pragma unroll
        for (int p = 0; p < 16; p++) s += red[tid * 16 + p];
        v1[tid] = s;
    }
    __syncthreads();
    // h1[o] = relu(sum_r a1[o,r]*v1[r] + bias1[o])
    for (int o = tid; o < H1D; o += 256) {
        const float* row = gb + OFF_A1 + o * RANK;
        float acc = gb[OFF_BIAS1 + o];
#pragma unroll
        for (int r = 0; r < RANK; r++) acc += row[r] * v1[r];
        h1s[o] = fmaxf(acc, 0.f);
    }
    __syncthreads();
    // v2[r] = sum_h b2f[r,h] * h1[h]
    {
        int r = tid >> 4, p = tid & 15;
        const float* row = gb + OFF_B2F + r * H1D;
        float acc = 0.f;
        for (int h = p; h < H1D; h += 16) acc += row[h] * h1s[h];
        red[tid] = acc;
    }
    __syncthreads();
    if (tid < 16) {
        float s = 0.f;
#pragma unroll
        for (int p = 0; p < 16; p++) s += red[tid * 16 + p];
        v2[tid] = s;
    }
    __syncthreads();
    if (tid < OUT_D) {
        const float* row = gb + OFF_A2 + tid * RANK;
        float acc = gb[OFF_BIAS2 + tid];
#pragma unroll
        for (int r = 0; r < RANK; r++) acc += row[r] * v2[r];
        out[b * OUT_D + tid] = acc;
    }
}

extern "C" void kernel_launch(void* const* d_in, const int* in_sizes, int n_in,
                              void* d_out, int out_size, void* d_ws, size_t ws_size,
                              hipStream_t stream) {
    const float* images = (const float*)d_in[0];
    const float* c1w = (const float*)d_in[1];
    const float* c1b = (const float*)d_in[2];
    const float* c2w = (const float*)d_in[3];
    const float* c2b = (const float*)d_in[4];
    const float* sew = (const float*)d_in[5];
    const float* seb = (const float*)d_in[6];
    const float* g1w = (const float*)d_in[7];
    const float* g1b = (const float*)d_in[8];
    const float* g2w = (const float*)d_in[9];
    const float* g2b = (const float*)d_in[10];
    float* out = (float*)d_out;

    float* ws = (float*)d_ws;
    float* h1c  = ws;                       // 256*16*14*14 = 802816
    float* h2c  = h1c + 802816;             // 256*32*7*7   = 401408
    float* s128 = h2c + 401408;             // 256*128      = 32768
    float* g    = s128 + 32768;             // 256*29610    = 7580160  (total ~35.3 MB)

    conv1_k<<<dim3((BSZ * 16 * 14 * 14 + 255) / 256), dim3(256), 0, stream>>>(images, c1w, c1b, h1c);
    conv2_k<<<dim3((BSZ * 32 * 7 * 7 + 255) / 256), dim3(256), 0, stream>>>(h1c, c2w, c2b, h2c);
    se_g1_k<<<dim3(BSZ), dim3(256), 0, stream>>>(h2c, sew, seb, g1w, g1b, s128);
    gmm_k<<<dim3((TOTAL + 511) / 512, 16), dim3(256), 0, stream>>>(s128, g2w, g2b, g);
    apply_k<<<dim3(BSZ), dim3(256), 0, stream>>>(images, g, out);
}

// Round 2
// 240.476 us; speedup vs baseline: 1.0267x; 1.0267x over previous
//
#include <hip/hip_runtime.h>
#include <math.h>

#define BSZ   256
#define RANK  16
#define IN_D  784
#define H1D   512
#define OUT_D 10
#define TOTAL 29610
#define GSTRIDE 29616   // padded row stride for g (16B-aligned rows)

// g layout offsets (per batch row)
#define OFF_A1    0        // 512*16 = 8192
#define OFF_B1F   8192     // 16*784 = 12544
#define OFF_BIAS1 20736    // 512
#define OFF_A2    21248    // 10*16 = 160
#define OFF_B2F   21408    // 16*512 = 8192
#define OFF_BIAS2 29600    // 10

// ---------------- conv1: (256,1,28,28) -> relu -> (256,16,14,14) ----------------
__global__ void conv1_k(const float* __restrict__ img, const float* __restrict__ w,
                        const float* __restrict__ bias, float* __restrict__ out) {
    int idx = blockIdx.x * 256 + threadIdx.x;
    if (idx >= BSZ * 16 * 14 * 14) return;
    int ox = idx % 14, oy = (idx / 14) % 14, oc = (idx / 196) % 16, b = idx / (196 * 16);
    float acc = bias[oc];
    const float* ib = img + b * 784;
    const float* wb = w + oc * 9;
#pragma unroll
    for (int ky = 0; ky < 3; ky++) {
        int iy = oy * 2 - 1 + ky;
        if ((unsigned)iy < 28u) {
#pragma unroll
            for (int kx = 0; kx < 3; kx++) {
                int ix = ox * 2 - 1 + kx;
                if ((unsigned)ix < 28u) acc += ib[iy * 28 + ix] * wb[ky * 3 + kx];
            }
        }
    }
    out[idx] = fmaxf(acc, 0.f);
}

// ---------------- conv2: (256,16,14,14) -> relu -> (256,32,7,7) ----------------
__global__ void conv2_k(const float* __restrict__ in, const float* __restrict__ w,
                        const float* __restrict__ bias, float* __restrict__ out) {
    int idx = blockIdx.x * 256 + threadIdx.x;
    if (idx >= BSZ * 32 * 7 * 7) return;
    int ox = idx % 7, oy = (idx / 7) % 7, oc = (idx / 49) % 32, b = idx / (49 * 32);
    float acc = bias[oc];
    const float* ib = in + b * 16 * 196;
    const float* wb = w + oc * 16 * 9;
    for (int ic = 0; ic < 16; ic++) {
        const float* ibc = ib + ic * 196;
        const float* wbc = wb + ic * 9;
#pragma unroll
        for (int ky = 0; ky < 3; ky++) {
            int iy = oy * 2 - 1 + ky;
            if ((unsigned)iy < 14u) {
#pragma unroll
                for (int kx = 0; kx < 3; kx++) {
                    int ix = ox * 2 - 1 + kx;
                    if ((unsigned)ix < 14u) acc += ibc[iy * 14 + ix] * wbc[ky * 3 + kx];
                }
            }
        }
    }
    out[idx] = fmaxf(acc, 0.f);
}

// ---------------- style = tanh(h2 @ sew.T + seb); s128 = relu(style @ g1w.T + g1b) ----------------
__global__ void se_g1_k(const float* __restrict__ h2, const float* __restrict__ sew,
                        const float* __restrict__ seb, const float* __restrict__ g1w,
                        const float* __restrict__ g1b, float* __restrict__ s128) {
    __shared__ float hrow[1568];
    __shared__ float red[64 * 4];
    __shared__ float style[64];
    int b = blockIdx.x, tid = threadIdx.x;
    {
        const float4* src = (const float4*)(h2 + b * 1568);
        float4* dst = (float4*)hrow;
        for (int i = tid; i < 392; i += 256) dst[i] = src[i];
    }
    __syncthreads();
    {
        int j = tid & 63, p = tid >> 6;  // 4 partials per output, float4 chunks
        const float4* wr = (const float4*)(sew + j * 1568);
        const float4* hr = (const float4*)hrow;
        float acc = 0.f;
        for (int k = p * 98; k < (p + 1) * 98; k++) {
            float4 w = wr[k], h = hr[k];
            acc += w.x * h.x + w.y * h.y + w.z * h.z + w.w * h.w;
        }
        red[j * 4 + p] = acc;
    }
    __syncthreads();
    if (tid < 64) {
        float a = red[tid * 4] + red[tid * 4 + 1] + red[tid * 4 + 2] + red[tid * 4 + 3] + seb[tid];
        style[tid] = tanhf(a);
    }
    __syncthreads();
    if (tid < 128) {
        const float* wr = g1w + tid * 64;
        float acc = g1b[tid];
#pragma unroll
        for (int k = 0; k < 64; k++) acc += wr[k] * style[k];
        s128[b * 128 + tid] = fmaxf(acc, 0.f);
    }
}

// ---------------- g[b][t] = dot128(s128[b], g2w[t]) + g2b[t] ----------------
// block: 128 threads, t-tile 256 (2 t per thread), 16 batches. grid 116 x 16.
__global__ __launch_bounds__(128, 4) void gmm_k(const float* __restrict__ s128,
                      const float* __restrict__ g2w,
                      const float* __restrict__ g2b, float* __restrict__ g) {
    __shared__ float sl[16 * 128];
    int tid = threadIdx.x;
    int tb0 = blockIdx.y * 16;
    int t0 = blockIdx.x * 256;
    {
        const float4* src = (const float4*)(s128 + tb0 * 128);
        float4* dst = (float4*)sl;
        for (int i = tid; i < 512; i += 128) dst[i] = src[i];
    }
    __syncthreads();
    int t = t0 + tid, t2 = t + 128;
    bool v1 = (t < TOTAL), v2 = (t2 < TOTAL);
    const float4* wa = (const float4*)(g2w + (v1 ? t : 0) * 128);
    const float4* wb = (const float4*)(g2w + (v2 ? t2 : 0) * 128);
    const float4* s4 = (const float4*)sl;
    float b1 = v1 ? g2b[t] : 0.f;
    float b2 = v2 ? g2b[t2] : 0.f;
    float acc[2][16];
#pragma unroll
    for (int j = 0; j < 16; j++) { acc[0][j] = b1; acc[1][j] = b2; }
#pragma unroll 4
    for (int kk = 0; kk < 32; kk++) {
        float4 w0 = wa[kk];
        float4 w1 = wb[kk];
#pragma unroll
        for (int j = 0; j < 16; j++) {
            float4 s = s4[j * 32 + kk];
            acc[0][j] += w0.x * s.x + w0.y * s.y + w0.z * s.z + w0.w * s.w;
            acc[1][j] += w1.x * s.x + w1.y * s.y + w1.z * s.z + w1.w * s.w;
        }
    }
#pragma unroll
    for (int j = 0; j < 16; j++) {
        if (v1) g[(tb0 + j) * GSTRIDE + t]  = acc[0][j];
        if (v2) g[(tb0 + j) * GSTRIDE + t2] = acc[1][j];
    }
}

// ---------------- per-batch low-rank apply (512 threads/block) ----------------
__global__ __launch_bounds__(512) void apply_k(const float* __restrict__ img,
                        const float* __restrict__ g, float* __restrict__ out) {
    __shared__ float x[IN_D];
    __shared__ float red[512];
    __shared__ float v1[RANK];
    __shared__ float h1s[H1D];
    __shared__ float v2[RANK];
    int b = blockIdx.x, tid = threadIdx.x;
    const float* gb = g + b * GSTRIDE;
    {
        const float4* src = (const float4*)(img + b * IN_D);
        float4* dst = (float4*)x;
        if (tid < 196) dst[tid] = src[tid];
    }
    __syncthreads();
    // v1[r] = sum_i b1f[r,i] * x[i]   (16 r x 32 partials)
    {
        int r = tid >> 5, p = tid & 31;
        const float4* row = (const float4*)(gb + OFF_B1F + r * IN_D);
        const float4* x4 = (const float4*)x;
        float acc = 0.f;
        for (int i = p; i < 196; i += 32) {
            float4 w = row[i], xv = x4[i];
            acc += w.x * xv.x + w.y * xv.y + w.z * xv.z + w.w * xv.w;
        }
        red[tid] = acc;
    }
    __syncthreads();
    if (tid < 16) {
        float s = 0.f;
#pragma unroll
        for (int p = 0; p < 32; p++) s += red[tid * 32 + p];
        v1[tid] = s;
    }
    __syncthreads();
    // h1[o] = relu(a1[o,:] . v1 + bias1[o]), o = tid (512)
    {
        const float4* row = (const float4*)(gb + OFF_A1 + tid * RANK);
        float acc = gb[OFF_BIAS1 + tid];
        const float4* v14 = (const float4*)v1;
#pragma unroll
        for (int q = 0; q < 4; q++) {
            float4 a = row[q], v = v14[q];
            acc += a.x * v.x + a.y * v.y + a.z * v.z + a.w * v.w;
        }
        h1s[tid] = fmaxf(acc, 0.f);
    }
    __syncthreads();
    // v2[r] = sum_h b2f[r,h] * h1[h]  (16 r x 32 partials)
    {
        int r = tid >> 5, p = tid & 31;
        const float4* row = (const float4*)(gb + OFF_B2F + r * H1D);
        const float4* h4 = (const float4*)h1s;
        float acc = 0.f;
        for (int i = p; i < 128; i += 32) {
            float4 w = row[i], hv = h4[i];
            acc += w.x * hv.x + w.y * hv.y + w.z * hv.z + w.w * hv.w;
        }
        red[tid] = acc;
    }
    __syncthreads();
    if (tid < 16) {
        float s = 0.f;
#pragma unroll
        for (int p = 0; p < 32; p++) s += red[tid * 32 + p];
        v2[tid] = s;
    }
    __syncthreads();
    if (tid < OUT_D) {
        const float* row = gb + OFF_A2 + tid * RANK;
        float acc = gb[OFF_BIAS2 + tid];
#pragma unroll
        for (int r = 0; r < RANK; r++) acc += row[r] * v2[r];
        out[b * OUT_D + tid] = acc;
    }
}

extern "C" void kernel_launch(void* const* d_in, const int* in_sizes, int n_in,
                              void* d_out, int out_size, void* d_ws, size_t ws_size,
                              hipStream_t stream) {
    const float* images = (const float*)d_in[0];
    const float* c1w = (const float*)d_in[1];
    const float* c1b = (const float*)d_in[2];
    const float* c2w = (const float*)d_in[3];
    const float* c2b = (const float*)d_in[4];
    const float* sew = (const float*)d_in[5];
    const float* seb = (const float*)d_in[6];
    const float* g1w = (const float*)d_in[7];
    const float* g1b = (const float*)d_in[8];
    const float* g2w = (const float*)d_in[9];
    const float* g2b = (const float*)d_in[10];
    float* out = (float*)d_out;

    float* ws = (float*)d_ws;
    float* h1c  = ws;                       // 256*16*14*14 = 802816
    float* h2c  = h1c + 802816;             // 256*32*7*7   = 401408
    float* s128 = h2c + 401408;             // 256*128      = 32768
    float* g    = s128 + 32768;             // 256*29616    = 7581696  (~35.3 MB total)

    conv1_k<<<dim3((BSZ * 16 * 14 * 14 + 255) / 256), dim3(256), 0, stream>>>(images, c1w, c1b, h1c);
    conv2_k<<<dim3((BSZ * 32 * 7 * 7 + 255) / 256), dim3(256), 0, stream>>>(h1c, c2w, c2b, h2c);
    se_g1_k<<<dim3(BSZ), dim3(256), 0, stream>>>(h2c, sew, seb, g1w, g1b, s128);
    gmm_k<<<dim3((TOTAL + 255) / 256, 16), dim3(128), 0, stream>>>(s128, g2w, g2b, g);
    apply_k<<<dim3(BSZ), dim3(512), 0, stream>>>(images, g, out);
}

// Round 3
// 171.787 us; speedup vs baseline: 1.4372x; 1.3998x over previous
//
#include <hip/hip_runtime.h>
#include <math.h>

#define BSZ   256
#define RANK  16
#define IN_D  784
#define H1D   512
#define OUT_D 10
#define TOTAL 29610
#define GSTRIDE 29616   // padded g row stride (16B-aligned rows)
#define LDB 136         // padded LDS B row stride (bf16 elems)

// g layout offsets (per batch row)
#define OFF_A1    0        // 512*16 = 8192
#define OFF_B1F   8192     // 16*784 = 12544
#define OFF_BIAS1 20736    // 512
#define OFF_A2    21248    // 10*16 = 160
#define OFF_B2F   21408    // 16*512 = 8192
#define OFF_BIAS2 29600    // 10

typedef __attribute__((ext_vector_type(8))) short short8;   // 8 bf16 = 4 VGPR (MFMA A/B frag)
typedef __attribute__((ext_vector_type(4))) short short4v;
typedef __attribute__((ext_vector_type(4))) float f32x4;

__device__ __forceinline__ short f2bf(float f) {      // RNE fp32 -> bf16
    unsigned u = __float_as_uint(f);
    unsigned r = (u + 0x7fffu + ((u >> 16) & 1u)) >> 16;
    return (short)r;
}
__device__ __forceinline__ float bf2f(short s) {
    return __uint_as_float(((unsigned)(unsigned short)s) << 16);
}

// ---------------- fused conv1+conv2 per batch: img -> h2 (256 x 1568) ----------------
__global__ __launch_bounds__(256) void front_k(
    const float* __restrict__ img, const float* __restrict__ c1w, const float* __restrict__ c1b,
    const float* __restrict__ c2w, const float* __restrict__ c2b,
    float* __restrict__ h2g) {
    __shared__ float xs[784];
    __shared__ float w1s[144];
    __shared__ float b1s[16];
    __shared__ float h1p[16 * 14 * 16];   // [ic][iy][16] (cols 14,15 zero pad)
    __shared__ float c2ws[16 * 32 * 9];   // [ic][oc][9] -> oc-stride 9 words (bank-clean)
    __shared__ float b2s[32];
    int b = blockIdx.x, tid = threadIdx.x;
    for (int i = tid; i < 196; i += 256) ((float4*)xs)[i] = ((const float4*)(img + b * 784))[i];
    for (int i = tid; i < 144; i += 256) w1s[i] = c1w[i];
    if (tid < 16) b1s[tid] = c1b[tid];
    if (tid < 32) b2s[tid] = c2b[tid];
    for (int i = tid; i < 4608; i += 256) {
        int oc = i / 144, r = i % 144, ic = r / 9, t = r % 9;
        c2ws[(ic * 32 + oc) * 9 + t] = c2w[i];
    }
    for (int i = tid; i < 3584; i += 256) h1p[i] = 0.f;
    __syncthreads();
    // conv1: 16 oc x 14x14, stride 2 pad 1
    for (int o = tid; o < 3136; o += 256) {
        int oc = o / 196, pos = o % 196, oy = pos / 14, ox = pos % 14;
        float acc = b1s[oc];
        const float* wb = &w1s[oc * 9];
#pragma unroll
        for (int ky = 0; ky < 3; ky++) {
            int iy = oy * 2 - 1 + ky;
            if ((unsigned)iy < 28u) {
#pragma unroll
                for (int kx = 0; kx < 3; kx++) {
                    int ix = ox * 2 - 1 + kx;
                    if ((unsigned)ix < 28u) acc += xs[iy * 28 + ix] * wb[ky * 3 + kx];
                }
            }
        }
        h1p[oc * 224 + oy * 16 + ox] = fmaxf(acc, 0.f);
    }
    __syncthreads();
    // conv2: 32 oc x 7x7, stride 2 pad 1. thread = (oc = tid&31, oy = tid>>5); oy<7 active.
    int oc = tid & 31, oy = tid >> 5;
    if (oy < 7) {
        float a7[7];
#pragma unroll
        for (int ox = 0; ox < 7; ox++) a7[ox] = b2s[oc];
        for (int ic = 0; ic < 16; ic++) {
            float w[9];
            const float* wp = &c2ws[(ic * 32 + oc) * 9];
#pragma unroll
            for (int t = 0; t < 9; t++) w[t] = wp[t];
            float rb[3][16];
#pragma unroll
            for (int ky = 0; ky < 3; ky++) {
                int iy = oy * 2 - 1 + ky;
                if ((unsigned)iy < 14u) {
                    const float4* rp = (const float4*)&h1p[ic * 224 + iy * 16];
#pragma unroll
                    for (int q = 0; q < 4; q++) {
                        float4 v = rp[q];
                        rb[ky][q * 4 + 0] = v.x; rb[ky][q * 4 + 1] = v.y;
                        rb[ky][q * 4 + 2] = v.z; rb[ky][q * 4 + 3] = v.w;
                    }
                } else {
#pragma unroll
                    for (int q = 0; q < 16; q++) rb[ky][q] = 0.f;
                }
            }
#pragma unroll
            for (int ox = 0; ox < 7; ox++) {
#pragma unroll
                for (int ky = 0; ky < 3; ky++) {
#pragma unroll
                    for (int kx = 0; kx < 3; kx++) {
                        int ix = 2 * ox + kx - 1;
                        if (ix >= 0) a7[ox] += rb[ky][ix] * w[ky * 3 + kx];
                    }
                }
            }
        }
        float* dst = h2g + b * 1568 + oc * 49 + oy * 7;
#pragma unroll
        for (int ox = 0; ox < 7; ox++) dst[ox] = fmaxf(a7[ox], 0.f);
    }
}

// ---------------- style = tanh(h2 @ sew.T + seb); s = relu(style @ g1w.T + g1b) -> bf16 hi/lo split ----------------
__global__ __launch_bounds__(512) void style_k(
    const float* __restrict__ h2g, const float* __restrict__ sew, const float* __restrict__ seb,
    const float* __restrict__ g1w, const float* __restrict__ g1b,
    short* __restrict__ Shi, short* __restrict__ Slo) {
    __shared__ float h2l[1568];
    __shared__ float red[512];
    __shared__ float style[64];
    int b = blockIdx.x, tid = threadIdx.x;
    if (tid < 392) ((float4*)h2l)[tid] = ((const float4*)(h2g + b * 1568))[tid];
    __syncthreads();
    {
        int j = tid & 63, p = tid >> 6;   // 64 outputs x 8 K-partials
        const float4* wr = (const float4*)(sew + j * 1568) + p * 49;
        const float4* hr = (const float4*)h2l + p * 49;
        float acc = 0.f;
#pragma unroll 7
        for (int i = 0; i < 49; i++) {
            float4 w = wr[i], h = hr[i];
            acc += w.x * h.x + w.y * h.y + w.z * h.z + w.w * h.w;
        }
        red[p * 64 + j] = acc;
    }
    __syncthreads();
    if (tid < 64) {
        float a = seb[tid];
#pragma unroll
        for (int p = 0; p < 8; p++) a += red[p * 64 + tid];
        style[tid] = tanhf(a);
    }
    __syncthreads();
    if (tid < 128) {
        const float4* wr = (const float4*)(g1w + tid * 64);
        const float4* sv = (const float4*)style;
        float acc = g1b[tid];
#pragma unroll
        for (int q = 0; q < 16; q++) {
            float4 w = wr[q], s = sv[q];
            acc += w.x * s.x + w.y * s.y + w.z * s.z + w.w * s.w;
        }
        float v = fmaxf(acc, 0.f);
        short hi = f2bf(v);
        Shi[b * 128 + tid] = hi;
        Slo[b * 128 + tid] = f2bf(v - bf2f(hi));
    }
}

// ---------------- g[b][t] = S[b,:128] . W[t,:128] + g2b[t], bf16x3 MFMA ----------------
// grid 232, block 256 (4 waves). M=256 (all batches), N-tile 128, K=128 (x3 passes).
// wave w: m rows [64w, 64w+64) = 4 m-tiles x 8 n-tiles; A frags in regs; B hi/lo in LDS.
__global__ __launch_bounds__(256, 1) void gemm_k(
    const short* __restrict__ Shi, const short* __restrict__ Slo,
    const float* __restrict__ g2w, const float* __restrict__ g2b,
    float* __restrict__ g) {
    __shared__ short Bhi[128 * LDB];
    __shared__ short Blo[128 * LDB];
    int tid = threadIdx.x;
    int n0 = blockIdx.x * 128;
    // stage + split B tile: 2 threads per row, 64 floats each
    {
        int r = tid >> 1, h = tid & 1;
        int t = n0 + r;
        short* dhi = Bhi + r * LDB + h * 64;
        short* dlo = Blo + r * LDB + h * 64;
        if (t < TOTAL) {
            const float4* src = (const float4*)(g2w + (long)t * 128 + h * 64);
#pragma unroll
            for (int i = 0; i < 16; i++) {
                float4 wv = src[i];
                short4v ph, pl;
                ph.x = f2bf(wv.x); ph.y = f2bf(wv.y); ph.z = f2bf(wv.z); ph.w = f2bf(wv.w);
                pl.x = f2bf(wv.x - bf2f(ph.x)); pl.y = f2bf(wv.y - bf2f(ph.y));
                pl.z = f2bf(wv.z - bf2f(ph.z)); pl.w = f2bf(wv.w - bf2f(ph.w));
                *(short4v*)(dhi + i * 4) = ph;
                *(short4v*)(dlo + i * 4) = pl;
            }
        } else {
            short4v z = {0, 0, 0, 0};
#pragma unroll
            for (int i = 0; i < 16; i++) { *(short4v*)(dhi + i * 4) = z; *(short4v*)(dlo + i * 4) = z; }
        }
    }
    __syncthreads();
    int lane = tid & 63, w = tid >> 6;
    int col = lane & 15, quad = lane >> 4;
    int mbase = w * 64;
    // A fragments (S hi/lo), held in registers: A[m = lane&15][k = quad*8+j]
    short8 Ah[4][4], Al[4][4];
#pragma unroll
    for (int mt = 0; mt < 4; mt++) {
#pragma unroll
        for (int ks = 0; ks < 4; ks++) {
            int row = mbase + mt * 16 + col;
            Ah[mt][ks] = *(const short8*)(Shi + row * 128 + ks * 32 + quad * 8);
            Al[mt][ks] = *(const short8*)(Slo + row * 128 + ks * 32 + quad * 8);
        }
    }
    f32x4 acc[4][8];
#pragma unroll
    for (int mt = 0; mt < 4; mt++)
#pragma unroll
        for (int nt = 0; nt < 8; nt++) acc[mt][nt] = (f32x4){0.f, 0.f, 0.f, 0.f};
#pragma unroll
    for (int nt = 0; nt < 8; nt++) {
#pragma unroll
        for (int ks = 0; ks < 4; ks++) {
            int bofs = (nt * 16 + col) * LDB + ks * 32 + quad * 8;
            short8 bh = *(const short8*)(Bhi + bofs);
            short8 bl = *(const short8*)(Blo + bofs);
#pragma unroll
            for (int mt = 0; mt < 4; mt++) {
                acc[mt][nt] = __builtin_amdgcn_mfma_f32_16x16x32_bf16(Ah[mt][ks], bh, acc[mt][nt], 0, 0, 0);
                acc[mt][nt] = __builtin_amdgcn_mfma_f32_16x16x32_bf16(Al[mt][ks], bh, acc[mt][nt], 0, 0, 0);
                acc[mt][nt] = __builtin_amdgcn_mfma_f32_16x16x32_bf16(Ah[mt][ks], bl, acc[mt][nt], 0, 0, 0);
            }
        }
    }
    // epilogue: C col = lane&15 (t), row = quad*4 + j (batch)
#pragma unroll
    for (int nt = 0; nt < 8; nt++) {
        int tcol = n0 + nt * 16 + col;
        if (tcol < TOTAL) {
            float bias = g2b[tcol];
#pragma unroll
            for (int mt = 0; mt < 4; mt++) {
                int rbase = mbase + mt * 16 + quad * 4;
#pragma unroll
                for (int j = 0; j < 4; j++)
                    g[(long)(rbase + j) * GSTRIDE + tcol] = acc[mt][nt][j] + bias;
            }
        }
    }
}

// ---------------- per-batch low-rank apply (512 threads/block) ----------------
__global__ __launch_bounds__(512) void apply_k(const float* __restrict__ img,
                        const float* __restrict__ g, float* __restrict__ out) {
    __shared__ float x[IN_D];
    __shared__ float red[512];
    __shared__ float v1[RANK];
    __shared__ float h1s[H1D];
    __shared__ float v2[RANK];
    int b = blockIdx.x, tid = threadIdx.x;
    const float* gb = g + (long)b * GSTRIDE;
    {
        const float4* src = (const float4*)(img + b * IN_D);
        float4* dst = (float4*)x;
        if (tid < 196) dst[tid] = src[tid];
    }
    __syncthreads();
    {
        int r = tid >> 5, p = tid & 31;
        const float4* row = (const float4*)(gb + OFF_B1F + r * IN_D);
        const float4* x4 = (const float4*)x;
        float acc = 0.f;
        for (int i = p; i < 196; i += 32) {
            float4 w = row[i], xv = x4[i];
            acc += w.x * xv.x + w.y * xv.y + w.z * xv.z + w.w * xv.w;
        }
        red[tid] = acc;
    }
    __syncthreads();
    if (tid < 16) {
        float s = 0.f;
#pragma unroll
        for (int p = 0; p < 32; p++) s += red[tid * 32 + p];
        v1[tid] = s;
    }
    __syncthreads();
    {
        const float4* row = (const float4*)(gb + OFF_A1 + tid * RANK);
        float acc = gb[OFF_BIAS1 + tid];
        const float4* v14 = (const float4*)v1;
#pragma unroll
        for (int q = 0; q < 4; q++) {
            float4 a = row[q], v = v14[q];
            acc += a.x * v.x + a.y * v.y + a.z * v.z + a.w * v.w;
        }
        h1s[tid] = fmaxf(acc, 0.f);
    }
    __syncthreads();
    {
        int r = tid >> 5, p = tid & 31;
        const float4* row = (const float4*)(gb + OFF_B2F + r * H1D);
        const float4* h4 = (const float4*)h1s;
        float acc = 0.f;
        for (int i = p; i < 128; i += 32) {
            float4 w = row[i], hv = h4[i];
            acc += w.x * hv.x + w.y * hv.y + w.z * hv.z + w.w * hv.w;
        }
        red[tid] = acc;
    }
    __syncthreads();
    if (tid < 16) {
        float s = 0.f;
#pragma unroll
        for (int p = 0; p < 32; p++) s += red[tid * 32 + p];
        v2[tid] = s;
    }
    __syncthreads();
    if (tid < OUT_D) {
        const float* row = gb + OFF_A2 + tid * RANK;
        float acc = gb[OFF_BIAS2 + tid];
#pragma unroll
        for (int r = 0; r < RANK; r++) acc += row[r] * v2[r];
        out[b * OUT_D + tid] = acc;
    }
}

extern "C" void kernel_launch(void* const* d_in, const int* in_sizes, int n_in,
                              void* d_out, int out_size, void* d_ws, size_t ws_size,
                              hipStream_t stream) {
    const float* images = (const float*)d_in[0];
    const float* c1w = (const float*)d_in[1];
    const float* c1b = (const float*)d_in[2];
    const float* c2w = (const float*)d_in[3];
    const float* c2b = (const float*)d_in[4];
    const float* sew = (const float*)d_in[5];
    const float* seb = (const float*)d_in[6];
    const float* g1w = (const float*)d_in[7];
    const float* g1b = (const float*)d_in[8];
    const float* g2w = (const float*)d_in[9];
    const float* g2b = (const float*)d_in[10];
    float* out = (float*)d_out;

    float* ws = (float*)d_ws;
    float* h2g = ws;                          // 256*1568 = 401408 floats
    short* Shi = (short*)(ws + 401408);       // 256*128 bf16
    short* Slo = Shi + 32768;                 // 256*128 bf16
    float* g   = ws + 401408 + 32768;         // 256*29616 floats (~30.3 MB); total ~32.1 MB

    front_k<<<dim3(BSZ), dim3(256), 0, stream>>>(images, c1w, c1b, c2w, c2b, h2g);
    style_k<<<dim3(BSZ), dim3(512), 0, stream>>>(h2g, sew, seb, g1w, g1b, Shi, Slo);
    gemm_k<<<dim3((TOTAL + 127) / 128), dim3(256), 0, stream>>>(Shi, Slo, g2w, g2b, g);
    apply_k<<<dim3(BSZ), dim3(512), 0, stream>>>(images, g, out);
}

// Round 4
// 138.366 us; speedup vs baseline: 1.7843x; 1.2415x over previous
//
#include <hip/hip_runtime.h>
#include <math.h>

#define BSZ   256
#define RANK  16
#define IN_D  784
#define H1D   512
#define OUT_D 10
#define TOTAL 29610
#define GSTRIDE 29616   // padded g row stride (16B-aligned rows)
#define LDB 136         // padded LDS B row stride (bf16 elems)

// g layout offsets (per batch row)
#define OFF_A1    0        // 512*16 = 8192
#define OFF_B1F   8192     // 16*784 = 12544
#define OFF_BIAS1 20736    // 512
#define OFF_A2    21248    // 10*16 = 160
#define OFF_B2F   21408    // 16*512 = 8192
#define OFF_BIAS2 29600    // 10

typedef __attribute__((ext_vector_type(8))) short short8;   // 8 bf16 = 4 VGPR (MFMA A/B frag)
typedef __attribute__((ext_vector_type(4))) short short4v;
typedef __attribute__((ext_vector_type(4))) float f32x4;

__device__ __forceinline__ short f2bf(float f) {      // RNE fp32 -> bf16
    unsigned u = __float_as_uint(f);
    unsigned r = (u + 0x7fffu + ((u >> 16) & 1u)) >> 16;
    return (short)r;
}
__device__ __forceinline__ float bf2f(short s) {
    return __uint_as_float(((unsigned)(unsigned short)s) << 16);
}

// ---------------- fused conv1+conv2 per batch: img -> h2 (256 x 1568) ----------------
// conv2 ic-loop kept at unroll 1: full unroll (trip 16) spilled at VGPR=256 in round 3.
__global__ __launch_bounds__(256) void front_k(
    const float* __restrict__ img, const float* __restrict__ c1w, const float* __restrict__ c1b,
    const float* __restrict__ c2w, const float* __restrict__ c2b,
    float* __restrict__ h2g) {
    __shared__ float xs[784];
    __shared__ float w1s[144];
    __shared__ float b1s[16], b2s[32];
    __shared__ float h1p[16 * 14 * 16];   // [ic][iy][16] (cols 14,15 unused)
    __shared__ float c2ws[32 * 144];      // native [oc][ic*9+t]; lane stride 144w -> 2-way (free)
    int b = blockIdx.x, tid = threadIdx.x;
    for (int i = tid; i < 196; i += 256) ((float4*)xs)[i] = ((const float4*)(img + b * 784))[i];
    for (int i = tid; i < 144; i += 256) w1s[i] = c1w[i];
    for (int i = tid; i < 1152; i += 256) ((float4*)c2ws)[i] = ((const float4*)c2w)[i];
    if (tid < 16) b1s[tid] = c1b[tid];
    if (tid < 32) b2s[tid] = c2b[tid];
    __syncthreads();
    // conv1: 16 oc x 14x14, stride 2 pad 1
#pragma unroll 1
    for (int o = tid; o < 3136; o += 256) {
        int oc = o / 196, pos = o % 196, oy = pos / 14, ox = pos % 14;
        float acc = b1s[oc];
        const float* wb = &w1s[oc * 9];
#pragma unroll
        for (int ky = 0; ky < 3; ky++) {
            int iy = oy * 2 - 1 + ky;
            if ((unsigned)iy < 28u) {
#pragma unroll
                for (int kx = 0; kx < 3; kx++) {
                    int ix = ox * 2 - 1 + kx;
                    if ((unsigned)ix < 28u) acc += xs[iy * 28 + ix] * wb[ky * 3 + kx];
                }
            }
        }
        h1p[oc * 224 + oy * 16 + ox] = fmaxf(acc, 0.f);
    }
    __syncthreads();
    // conv2: 32 oc x 7x7. thread = (oc = tid&31, oy = tid>>5); oy<7 active.
    int oc = tid & 31, oy = tid >> 5;
    if (oy < 7) {
        float a7[7];
#pragma unroll
        for (int ox = 0; ox < 7; ox++) a7[ox] = b2s[oc];
#pragma unroll 1
        for (int ic = 0; ic < 16; ic++) {
            const float* wp = &c2ws[oc * 144 + ic * 9];
            float w[9];
#pragma unroll
            for (int t = 0; t < 9; t++) w[t] = wp[t];
#pragma unroll
            for (int ky = 0; ky < 3; ky++) {
                int iy = oy * 2 - 1 + ky;
                if ((unsigned)iy < 14u) {
                    const float4* rp = (const float4*)&h1p[ic * 224 + iy * 16];
                    float r[16];
#pragma unroll
                    for (int q = 0; q < 4; q++) {
                        float4 v = rp[q];
                        r[q * 4 + 0] = v.x; r[q * 4 + 1] = v.y;
                        r[q * 4 + 2] = v.z; r[q * 4 + 3] = v.w;
                    }
#pragma unroll
                    for (int ox = 0; ox < 7; ox++) {
#pragma unroll
                        for (int kx = 0; kx < 3; kx++) {
                            int ix = 2 * ox + kx - 1;
                            if (ix >= 0) a7[ox] += r[ix] * w[ky * 3 + kx];
                        }
                    }
                }
            }
        }
        float* dst = h2g + b * 1568 + oc * 49 + oy * 7;
#pragma unroll
        for (int ox = 0; ox < 7; ox++) dst[ox] = fmaxf(a7[ox], 0.f);
    }
}

// ---------------- style = tanh(h2 @ sew.T + seb); s = relu(style @ g1w.T + g1b) -> bf16 hi/lo ----------------
__global__ __launch_bounds__(512) void style_k(
    const float* __restrict__ h2g, const float* __restrict__ sew, const float* __restrict__ seb,
    const float* __restrict__ g1w, const float* __restrict__ g1b,
    short* __restrict__ Shi, short* __restrict__ Slo) {
    __shared__ float h2l[1568];
    __shared__ float red[512];
    __shared__ float style[64];
    int b = blockIdx.x, tid = threadIdx.x;
    if (tid < 392) ((float4*)h2l)[tid] = ((const float4*)(h2g + b * 1568))[tid];
    __syncthreads();
    {
        int j = tid & 63, p = tid >> 6;   // 64 outputs x 8 K-partials
        const float4* wr = (const float4*)(sew + j * 1568) + p * 49;
        const float4* hr = (const float4*)h2l + p * 49;
        float acc = 0.f;
#pragma unroll 7
        for (int i = 0; i < 49; i++) {
            float4 w = wr[i], h = hr[i];
            acc += w.x * h.x + w.y * h.y + w.z * h.z + w.w * h.w;
        }
        red[p * 64 + j] = acc;
    }
    __syncthreads();
    if (tid < 64) {
        float a = seb[tid];
#pragma unroll
        for (int p = 0; p < 8; p++) a += red[p * 64 + tid];
        style[tid] = tanhf(a);
    }
    __syncthreads();
    if (tid < 128) {
        const float4* wr = (const float4*)(g1w + tid * 64);
        const float4* sv = (const float4*)style;
        float acc = g1b[tid];
#pragma unroll
        for (int q = 0; q < 16; q++) {
            float4 w = wr[q], s = sv[q];
            acc += w.x * s.x + w.y * s.y + w.z * s.z + w.w * s.w;
        }
        float v = fmaxf(acc, 0.f);
        short hi = f2bf(v);
        Shi[b * 128 + tid] = hi;
        Slo[b * 128 + tid] = f2bf(v - bf2f(hi));
    }
}

// ---------------- g[b][t] = S[b,:128] . W[t,:128] + g2b[t], bf16x3 MFMA ----------------
// grid (232, 2), block 512 (8 waves). blockIdx.y selects M-half (128 batches),
// wave w owns 1 m-tile (16 rows); N-tile 128 = 8 n-tiles; K=128.
// Light registers: A frags 2x4x(4VGPR)=32, acc 8x4=32 -> no spill.
__global__ __launch_bounds__(512, 1) void gemm_k(
    const short* __restrict__ Shi, const short* __restrict__ Slo,
    const float* __restrict__ g2w, const float* __restrict__ g2b,
    float* __restrict__ g) {
    __shared__ short Bhi[128 * LDB];
    __shared__ short Blo[128 * LDB];
    int tid = threadIdx.x;
    int n0 = blockIdx.x * 128;
    int m0 = blockIdx.y * 128;
    // stage + split B tile: 4 threads per row, 32 floats each
    {
        int r = tid >> 2, h = tid & 3;
        int t = n0 + r;
        short* dhi = Bhi + r * LDB + h * 32;
        short* dlo = Blo + r * LDB + h * 32;
        if (t < TOTAL) {
            const float4* src = (const float4*)(g2w + (long)t * 128 + h * 32);
#pragma unroll
            for (int i = 0; i < 8; i++) {
                float4 wv = src[i];
                short4v ph, pl;
                ph.x = f2bf(wv.x); ph.y = f2bf(wv.y); ph.z = f2bf(wv.z); ph.w = f2bf(wv.w);
                pl.x = f2bf(wv.x - bf2f(ph.x)); pl.y = f2bf(wv.y - bf2f(ph.y));
                pl.z = f2bf(wv.z - bf2f(ph.z)); pl.w = f2bf(wv.w - bf2f(ph.w));
                *(short4v*)(dhi + i * 4) = ph;
                *(short4v*)(dlo + i * 4) = pl;
            }
        } else {
            short4v z = {0, 0, 0, 0};
#pragma unroll
            for (int i = 0; i < 8; i++) { *(short4v*)(dhi + i * 4) = z; *(short4v*)(dlo + i * 4) = z; }
        }
    }
    __syncthreads();
    int lane = tid & 63, w = tid >> 6;
    int col = lane & 15, quad = lane >> 4;
    int mrow = m0 + w * 16 + col;
    // A fragments: A[m = lane&15][k = quad*8+j]
    short8 Ah[4], Al[4];
#pragma unroll
    for (int ks = 0; ks < 4; ks++) {
        Ah[ks] = *(const short8*)(Shi + mrow * 128 + ks * 32 + quad * 8);
        Al[ks] = *(const short8*)(Slo + mrow * 128 + ks * 32 + quad * 8);
    }
    f32x4 acc[8];
#pragma unroll
    for (int nt = 0; nt < 8; nt++) acc[nt] = (f32x4){0.f, 0.f, 0.f, 0.f};
#pragma unroll
    for (int nt = 0; nt < 8; nt++) {
#pragma unroll
        for (int ks = 0; ks < 4; ks++) {
            int bofs = (nt * 16 + col) * LDB + ks * 32 + quad * 8;
            short8 bh = *(const short8*)(Bhi + bofs);
            short8 bl = *(const short8*)(Blo + bofs);
            acc[nt] = __builtin_amdgcn_mfma_f32_16x16x32_bf16(Ah[ks], bh, acc[nt], 0, 0, 0);
            acc[nt] = __builtin_amdgcn_mfma_f32_16x16x32_bf16(Al[ks], bh, acc[nt], 0, 0, 0);
            acc[nt] = __builtin_amdgcn_mfma_f32_16x16x32_bf16(Ah[ks], bl, acc[nt], 0, 0, 0);
        }
    }
    // epilogue: C col = lane&15 (t), row = quad*4 + j (batch)
#pragma unroll
    for (int nt = 0; nt < 8; nt++) {
        int tcol = n0 + nt * 16 + col;
        if (tcol < TOTAL) {
            float bias = g2b[tcol];
            int rbase = m0 + w * 16 + quad * 4;
#pragma unroll
            for (int j = 0; j < 4; j++)
                g[(long)(rbase + j) * GSTRIDE + tcol] = acc[nt][j] + bias;
        }
    }
}

// ---------------- per-batch low-rank apply (512 threads/block) ----------------
__global__ __launch_bounds__(512) void apply_k(const float* __restrict__ img,
                        const float* __restrict__ g, float* __restrict__ out) {
    __shared__ float x[IN_D];
    __shared__ float red[512];
    __shared__ float v1[RANK];
    __shared__ float h1s[H1D];
    __shared__ float v2[RANK];
    int b = blockIdx.x, tid = threadIdx.x;
    const float* gb = g + (long)b * GSTRIDE;
    {
        const float4* src = (const float4*)(img + b * IN_D);
        float4* dst = (float4*)x;
        if (tid < 196) dst[tid] = src[tid];
    }
    __syncthreads();
    {
        int r = tid >> 5, p = tid & 31;
        const float4* row = (const float4*)(gb + OFF_B1F + r * IN_D);
        const float4* x4 = (const float4*)x;
        float acc = 0.f;
        for (int i = p; i < 196; i += 32) {
            float4 w = row[i], xv = x4[i];
            acc += w.x * xv.x + w.y * xv.y + w.z * xv.z + w.w * xv.w;
        }
        red[tid] = acc;
    }
    __syncthreads();
    if (tid < 16) {
        float s = 0.f;
#pragma unroll
        for (int p = 0; p < 32; p++) s += red[tid * 32 + p];
        v1[tid] = s;
    }
    __syncthreads();
    {
        const float4* row = (const float4*)(gb + OFF_A1 + tid * RANK);
        float acc = gb[OFF_BIAS1 + tid];
        const float4* v14 = (const float4*)v1;
#pragma unroll
        for (int q = 0; q < 4; q++) {
            float4 a = row[q], v = v14[q];
            acc += a.x * v.x + a.y * v.y + a.z * v.z + a.w * v.w;
        }
        h1s[tid] = fmaxf(acc, 0.f);
    }
    __syncthreads();
    {
        int r = tid >> 5, p = tid & 31;
        const float4* row = (const float4*)(gb + OFF_B2F + r * H1D);
        const float4* h4 = (const float4*)h1s;
        float acc = 0.f;
        for (int i = p; i < 128; i += 32) {
            float4 w = row[i], hv = h4[i];
            acc += w.x * hv.x + w.y * hv.y + w.z * hv.z + w.w * hv.w;
        }
        red[tid] = acc;
    }
    __syncthreads();
    if (tid < 16) {
        float s = 0.f;
#pragma unroll
        for (int p = 0; p < 32; p++) s += red[tid * 32 + p];
        v2[tid] = s;
    }
    __syncthreads();
    if (tid < OUT_D) {
        const float* row = gb + OFF_A2 + tid * RANK;
        float acc = gb[OFF_BIAS2 + tid];
#pragma unroll
        for (int r = 0; r < RANK; r++) acc += row[r] * v2[r];
        out[b * OUT_D + tid] = acc;
    }
}

extern "C" void kernel_launch(void* const* d_in, const int* in_sizes, int n_in,
                              void* d_out, int out_size, void* d_ws, size_t ws_size,
                              hipStream_t stream) {
    const float* images = (const float*)d_in[0];
    const float* c1w = (const float*)d_in[1];
    const float* c1b = (const float*)d_in[2];
    const float* c2w = (const float*)d_in[3];
    const float* c2b = (const float*)d_in[4];
    const float* sew = (const float*)d_in[5];
    const float* seb = (const float*)d_in[6];
    const float* g1w = (const float*)d_in[7];
    const float* g1b = (const float*)d_in[8];
    const float* g2w = (const float*)d_in[9];
    const float* g2b = (const float*)d_in[10];
    float* out = (float*)d_out;

    float* ws = (float*)d_ws;
    float* h2g = ws;                          // 256*1568 = 401408 floats
    short* Shi = (short*)(ws + 401408);       // 256*128 bf16
    short* Slo = Shi + 32768;                 // 256*128 bf16
    float* g   = ws + 401408 + 32768;         // 256*29616 floats (~30.3 MB); total ~32.1 MB

    front_k<<<dim3(BSZ), dim3(256), 0, stream>>>(images, c1w, c1b, c2w, c2b, h2g);
    style_k<<<dim3(BSZ), dim3(512), 0, stream>>>(h2g, sew, seb, g1w, g1b, Shi, Slo);
    gemm_k<<<dim3((TOTAL + 127) / 128, 2), dim3(512), 0, stream>>>(Shi, Slo, g2w, g2b, g);
    apply_k<<<dim3(BSZ), dim3(512), 0, stream>>>(images, g, out);
}